// Round 10
// baseline (353.817 us; speedup 1.0000x reference)
//
#include <hip/hip_runtime.h>

#define Bq 2
#define Hh 8
#define Ss 512
#define HD 64
#define DIM 512

using f32x4   = __attribute__((ext_vector_type(4))) float;
using bf16x8s = __attribute__((ext_vector_type(8))) short;
typedef _Float16 f16x8 __attribute__((ext_vector_type(8)));

__device__ __forceinline__ float bf2f(unsigned short u) {
    return __uint_as_float(((unsigned int)u) << 16);
}
__device__ __forceinline__ unsigned short f2bf(float f) {
    unsigned int u = __float_as_uint(f);
    u = (u + 0x7FFFu + ((u >> 16) & 1u)) >> 16;   // RNE
    return (unsigned short)u;
}

// ============ mm_k: C = A @ B^T + bias (fp32 io, split bf16x2 MFMA, 128x128) ============
__global__ __launch_bounds__(256) void mm_k(
    const float* __restrict__ A, const float* __restrict__ B,
    const float* __restrict__ bias, float* __restrict__ C,
    int K, int ldc)
{
    const int row0 = blockIdx.y * 128, col0 = blockIdx.x * 128;
    __shared__ unsigned short AsH[128][40], AsL[128][40];
    __shared__ unsigned short BsH[128][40], BsL[128][40];
    const int t = threadIdx.x;
    const int wave = t >> 6, lane = t & 63;
    const int ln = lane & 15, quad = lane >> 4;
    const int wm = (wave & 1) * 64, wn = (wave >> 1) * 64;

    f32x4 acc[4][4];
#pragma unroll
    for (int i = 0; i < 4; ++i)
#pragma unroll
        for (int j = 0; j < 4; ++j)
            acc[i][j] = (f32x4){0.f, 0.f, 0.f, 0.f};

    const int sr = t >> 2, sg = (t & 3) * 8;

    for (int k0 = 0; k0 < K; k0 += 32) {
        __syncthreads();
#pragma unroll
        for (int half = 0; half < 4; ++half) {
            const float* src = (half < 2) ? A : B;
            int base = (half < 2) ? row0 : col0;
            int row = sr + ((half & 1) ? 64 : 0);
            const float* p = &src[(long)(base + row) * K + k0 + sg];
            float4 f0 = *(const float4*)p;
            float4 f1 = *(const float4*)(p + 4);
            float fv[8] = {f0.x, f0.y, f0.z, f0.w, f1.x, f1.y, f1.z, f1.w};
            unsigned short hv[8], lv[8];
#pragma unroll
            for (int e = 0; e < 8; ++e) {
                hv[e] = f2bf(fv[e]);
                lv[e] = f2bf(fv[e] - bf2f(hv[e]));
            }
            uint4 H, L;
            H.x = hv[0] | (hv[1] << 16); H.y = hv[2] | (hv[3] << 16);
            H.z = hv[4] | (hv[5] << 16); H.w = hv[6] | (hv[7] << 16);
            L.x = lv[0] | (lv[1] << 16); L.y = lv[2] | (lv[3] << 16);
            L.z = lv[4] | (lv[5] << 16); L.w = lv[6] | (lv[7] << 16);
            if (half < 2) { *(uint4*)&AsH[row][sg] = H; *(uint4*)&AsL[row][sg] = L; }
            else          { *(uint4*)&BsH[row][sg] = H; *(uint4*)&BsL[row][sg] = L; }
        }
        __syncthreads();

        bf16x8s afH[4], afL[4], bfH[4], bfL[4];
#pragma unroll
        for (int mt = 0; mt < 4; ++mt) {
            afH[mt] = *(const bf16x8s*)&AsH[wm + mt * 16 + ln][quad * 8];
            afL[mt] = *(const bf16x8s*)&AsL[wm + mt * 16 + ln][quad * 8];
        }
#pragma unroll
        for (int nt = 0; nt < 4; ++nt) {
            bfH[nt] = *(const bf16x8s*)&BsH[wn + nt * 16 + ln][quad * 8];
            bfL[nt] = *(const bf16x8s*)&BsL[wn + nt * 16 + ln][quad * 8];
        }
#pragma unroll
        for (int mt = 0; mt < 4; ++mt)
#pragma unroll
            for (int nt = 0; nt < 4; ++nt) {
                acc[mt][nt] = __builtin_amdgcn_mfma_f32_16x16x32_bf16(afH[mt], bfH[nt], acc[mt][nt], 0, 0, 0);
                acc[mt][nt] = __builtin_amdgcn_mfma_f32_16x16x32_bf16(afH[mt], bfL[nt], acc[mt][nt], 0, 0, 0);
                acc[mt][nt] = __builtin_amdgcn_mfma_f32_16x16x32_bf16(afL[mt], bfH[nt], acc[mt][nt], 0, 0, 0);
            }
    }

#pragma unroll
    for (int mt = 0; mt < 4; ++mt) {
        const int gr0 = row0 + wm + mt * 16 + quad * 4;
#pragma unroll
        for (int nt = 0; nt < 4; ++nt) {
            const int gc = col0 + wn + nt * 16 + ln;
            float bb = bias[gc];
#pragma unroll
            for (int r = 0; r < 4; ++r)
                C[(long)(gr0 + r) * ldc + gc] = acc[mt][nt][r] + bb;
        }
    }
}

// ============ wt_fused: W fp16 (both layouts) + row/rowsq/col partials + vT ============
__global__ __launch_bounds__(256) void wt_fused(const float* __restrict__ qkv,
                                                _Float16* __restrict__ Wh,
                                                _Float16* __restrict__ Wt,
                                                _Float16* __restrict__ vT,
                                                float* __restrict__ rsum,
                                                float* __restrict__ rsq,
                                                float* __restrict__ csum)
{
    __shared__ float qs[32][128];
    __shared__ float ks[32][128];
    __shared__ float colacc[128];
    int z = blockIdx.y;
    int b = z >> 3, h = z & 7;
    int t = threadIdx.x;
    int bx = blockIdx.x;
    long zo = (long)z * Ss * Ss;

    if (bx >= 16) {            // vT pack: half dh
        float (*sT)[33] = (float(*)[33])qs;
        int dt = (bx - 16) * 32;
        int d = t & 31, kr = t >> 5;
        for (int kt = 0; kt < Ss; kt += 32) {
            __syncthreads();
#pragma unroll
            for (int p = 0; p < 4; ++p) {
                int kk = kr + p * 8;
                sT[kk][d] = qkv[(long)b * (Ss * 3 * DIM) + (long)(kt + kk) * (3 * DIM) + 2 * DIM + h * HD + dt + d];
            }
            __syncthreads();
#pragma unroll
            for (int p = 0; p < 4; ++p) {
                int dd = kr + p * 8;
                vT[(long)z * (HD * Ss) + (long)(dt + dd) * Ss + kt + d] = (_Float16)sT[d][dd];
            }
        }
        return;
    }

    int ti = bx >> 2, tj = bx & 3;
    int i0 = ti * 128, j0 = tj * 128;

    if (tj > ti) {             // fully-masked tile: zero both layouts + partial slots
        uint4 zz = make_uint4(0, 0, 0, 0);
#pragma unroll
        for (int r = 0; r < 8; ++r) {
            int idx = r * 256 + t;
            int row = idx >> 4, col16 = idx & 15;
            *(uint4*)&Wt[zo + (long)(j0 + row) * Ss + i0 + col16 * 8] = zz;
            *(uint4*)&Wh[zo + (long)(i0 + row) * Ss + j0 + col16 * 8] = zz;
        }
        if (t < 128) {
            rsum[((z * 4 + ti) * 512) + j0 + t] = 0.f;
            rsq [((z * 4 + ti) * 512) + j0 + t] = 0.f;
            csum[((z * 4 + tj) * 512) + i0 + t] = 0.f;
        }
        return;
    }

    int ia = (t & 15) * 4;
    int ja = (t >> 4) * 4;
    const float* qb = qkv + (long)b * Ss * (3 * DIM) + h * HD;
    const float* kb = qb + DIM;
    float acc[8][8] = {};

    for (int d0 = 0; d0 < 64; d0 += 32) {
        __syncthreads();
        int col = t & 127, dg = t >> 7;
#pragma unroll
        for (int e = 0; e < 4; ++e) {
            int d = dg * 16 + e * 4;
            float4 qv = *(const float4*)&qb[(long)(i0 + col) * (3 * DIM) + d0 + d];
            float4 kv = *(const float4*)&kb[(long)(j0 + col) * (3 * DIM) + d0 + d];
            qs[d+0][col] = qv.x; qs[d+1][col] = qv.y; qs[d+2][col] = qv.z; qs[d+3][col] = qv.w;
            ks[d+0][col] = kv.x; ks[d+1][col] = kv.y; ks[d+2][col] = kv.z; ks[d+3][col] = kv.w;
        }
        __syncthreads();
#pragma unroll
        for (int d = 0; d < 32; ++d) {
            float4 q0 = *(const float4*)&qs[d][ia];
            float4 q1 = *(const float4*)&qs[d][ia + 64];
            float4 k0 = *(const float4*)&ks[d][ja];
            float4 k1 = *(const float4*)&ks[d][ja + 64];
            float qv[8] = {q0.x,q0.y,q0.z,q0.w, q1.x,q1.y,q1.z,q1.w};
            float kv[8] = {k0.x,k0.y,k0.z,k0.w, k1.x,k1.y,k1.z,k1.w};
#pragma unroll
            for (int aa = 0; aa < 8; ++aa)
#pragma unroll
                for (int c = 0; c < 8; ++c)
                    acc[aa][c] += fabsf(qv[aa] - kv[c]);
        }
    }

#pragma unroll
    for (int aa = 0; aa < 8; ++aa) {
        int i = i0 + ia + (aa & 3) + ((aa >> 2) * 64);
#pragma unroll
        for (int c = 0; c < 8; ++c) {
            int j = j0 + ja + (c & 3) + ((c >> 2) * 64);
            float e = expf(-acc[aa][c] * 0.25f);
            acc[aa][c] = (j <= i) ? e : 0.0f;
        }
    }
#pragma unroll
    for (int c = 0; c < 8; ++c) {
        int j = j0 + ja + (c & 3) + ((c >> 2) * 64);
        float rs = 0.f, rq = 0.f;
#pragma unroll
        for (int aa = 0; aa < 8; ++aa) { rs += acc[aa][c]; rq += acc[aa][c] * acc[aa][c]; }
        _Float16 ha[4] __attribute__((aligned(8))) = {(_Float16)acc[0][c], (_Float16)acc[1][c], (_Float16)acc[2][c], (_Float16)acc[3][c]};
        _Float16 hb[4] __attribute__((aligned(8))) = {(_Float16)acc[4][c], (_Float16)acc[5][c], (_Float16)acc[6][c], (_Float16)acc[7][c]};
        *(uint2*)&Wt[zo + (long)j * Ss + i0 + ia]      = *(const uint2*)ha;
        *(uint2*)&Wt[zo + (long)j * Ss + i0 + 64 + ia] = *(const uint2*)hb;
#pragma unroll
        for (int off = 8; off > 0; off >>= 1) {
            rs += __shfl_down(rs, off, 16);
            rq += __shfl_down(rq, off, 16);
        }
        if ((t & 15) == 0) {
            rsum[((z * 4 + ti) * 512) + j] = rs;
            rsq [((z * 4 + ti) * 512) + j] = rq;
        }
    }
#pragma unroll
    for (int aa = 0; aa < 8; ++aa) {
        int i = i0 + ia + (aa & 3) + ((aa >> 2) * 64);
        _Float16 ha[4] __attribute__((aligned(8))) = {(_Float16)acc[aa][0], (_Float16)acc[aa][1], (_Float16)acc[aa][2], (_Float16)acc[aa][3]};
        _Float16 hb[4] __attribute__((aligned(8))) = {(_Float16)acc[aa][4], (_Float16)acc[aa][5], (_Float16)acc[aa][6], (_Float16)acc[aa][7]};
        *(uint2*)&Wh[zo + (long)i * Ss + j0 + ja]      = *(const uint2*)ha;
        *(uint2*)&Wh[zo + (long)i * Ss + j0 + 64 + ja] = *(const uint2*)hb;
    }
    __syncthreads();
    if (t < 128) colacc[t] = 0.f;
    __syncthreads();
#pragma unroll
    for (int aa = 0; aa < 8; ++aa) {
        float cs = 0.f;
#pragma unroll
        for (int c = 0; c < 8; ++c) cs += acc[aa][c];
        atomicAdd(&colacc[ia + (aa & 3) + ((aa >> 2) * 64)], cs);
    }
    __syncthreads();
    if (t < 128) csum[((z * 4 + tj) * 512) + i0 + t] = colacc[t];
}

// ============ fp16-A wide core (pipelined): acc += A[64xK] x B[64-chunk x K] ============
__device__ __forceinline__ void wk_core(char* smc, const _Float16* A, const _Float16* B,
                                        long zA, long zB, int col0, int kbeg, int kend,
                                        f32x4* acc)
{
    _Float16 (*As)[40] = (_Float16(*)[40])smc;
    _Float16 (*Bs)[40] = (_Float16(*)[40])(smc + 5120);
    const int t = threadIdx.x;
    const int wave = t >> 6, lane = t & 63;
    const int ln = lane & 15, quad = lane >> 4;
    const int r4 = t >> 2, c4 = (t & 3) * 8;
    const long aoff = zA + (long)r4 * Ss;
    const long boff = zB + (long)(col0 + r4) * Ss;

    uint4 ua = *(const uint4*)&A[aoff + kbeg + c4];
    uint4 ub = *(const uint4*)&B[boff + kbeg + c4];
    for (int k0 = kbeg; k0 < kend; k0 += 32) {
        *(uint4*)&As[r4][c4] = ua;
        *(uint4*)&Bs[r4][c4] = ub;
        __syncthreads();
        int kn = k0 + 32;
        if (kn < kend) {
            ua = *(const uint4*)&A[aoff + kn + c4];
            ub = *(const uint4*)&B[boff + kn + c4];
        }
        f16x8 af = *(const f16x8*)&As[wave * 16 + ln][quad * 8];
#pragma unroll
        for (int nt = 0; nt < 4; ++nt) {
            f16x8 bf = *(const f16x8*)&Bs[nt * 16 + ln][quad * 8];
            acc[nt] = __builtin_amdgcn_mfma_f32_16x16x32_f16(af, bf, acc[nt], 0, 0, 0);
        }
        __syncthreads();
    }
}

// ============ fp32-halves-A wide core: A = A0+A1 (fp32), converted in staging ============
__device__ __forceinline__ void wk_core32(char* smc, const float* A0, const float* A1,
                                          const _Float16* B, long zA, long zB, int col0,
                                          int kbeg, int kend, f32x4* acc)
{
    _Float16 (*As)[40] = (_Float16(*)[40])smc;
    _Float16 (*Bs)[40] = (_Float16(*)[40])(smc + 5120);
    const int t = threadIdx.x;
    const int wave = t >> 6, lane = t & 63;
    const int ln = lane & 15, quad = lane >> 4;
    const int r4 = t >> 2, c4 = (t & 3) * 8;
    const long aoff = zA + (long)r4 * Ss;
    const long boff = zB + (long)(col0 + r4) * Ss;

    float4 p0 = *(const float4*)&A0[aoff + kbeg + c4];
    float4 p1 = *(const float4*)&A0[aoff + kbeg + c4 + 4];
    float4 q0 = *(const float4*)&A1[aoff + kbeg + c4];
    float4 q1 = *(const float4*)&A1[aoff + kbeg + c4 + 4];
    uint4 ub = *(const uint4*)&B[boff + kbeg + c4];
    for (int k0 = kbeg; k0 < kend; k0 += 32) {
        _Float16 hv[8] __attribute__((aligned(16)));
        hv[0] = (_Float16)(p0.x + q0.x); hv[1] = (_Float16)(p0.y + q0.y);
        hv[2] = (_Float16)(p0.z + q0.z); hv[3] = (_Float16)(p0.w + q0.w);
        hv[4] = (_Float16)(p1.x + q1.x); hv[5] = (_Float16)(p1.y + q1.y);
        hv[6] = (_Float16)(p1.z + q1.z); hv[7] = (_Float16)(p1.w + q1.w);
        *(uint4*)&As[r4][c4] = *(const uint4*)hv;
        *(uint4*)&Bs[r4][c4] = ub;
        __syncthreads();
        int kn = k0 + 32;
        if (kn < kend) {
            p0 = *(const float4*)&A0[aoff + kn + c4];
            p1 = *(const float4*)&A0[aoff + kn + c4 + 4];
            q0 = *(const float4*)&A1[aoff + kn + c4];
            q1 = *(const float4*)&A1[aoff + kn + c4 + 4];
            ub = *(const uint4*)&B[boff + kn + c4];
        }
        f16x8 af = *(const f16x8*)&As[wave * 16 + ln][quad * 8];
#pragma unroll
        for (int nt = 0; nt < 4; ++nt) {
            f16x8 bf = *(const f16x8*)&Bs[nt * 16 + ln][quad * 8];
            acc[nt] = __builtin_amdgcn_mfma_f32_16x16x32_f16(af, bf, acc[nt], 0, 0, 0);
        }
        __syncthreads();
    }
}

// ============ mid_k: blocks 0..127 -> y0 = vT x Wt (fp32); 128..151 -> fin ============
__global__ __launch_bounds__(256) void mid_k(const _Float16* __restrict__ vT,
                                             const _Float16* __restrict__ Wt,
                                             float* __restrict__ y0,
                                             const float* __restrict__ rsum,
                                             const float* __restrict__ rsq,
                                             const float* __restrict__ csum,
                                             float* __restrict__ scal,
                                             float* __restrict__ mu,
                                             float* __restrict__ inv_sig)
{
    __shared__ __align__(16) char sm[10240];
    int bx = blockIdx.x, t = threadIdx.x;
    if (bx < 128) {
        int z = bx >> 3, cc = bx & 7;
        int col0 = cc * 64;
        long zA = (long)z * (HD * Ss), zB = (long)z * Ss * Ss;
        f32x4 acc[4];
#pragma unroll
        for (int i = 0; i < 4; ++i) acc[i] = (f32x4){0.f, 0.f, 0.f, 0.f};
        wk_core(sm, vT, Wt, zA, zB, col0, col0, Ss, acc);
        const int wave = t >> 6, lane = t & 63;
        const int ln = lane & 15, quad = lane >> 4;
        const int gr = wave * 16 + quad * 4;
#pragma unroll
        for (int nt = 0; nt < 4; ++nt) {
            const int gc = col0 + nt * 16 + ln;
#pragma unroll
            for (int r = 0; r < 4; ++r)
                y0[zA + (long)(gr + r) * Ss + gc] = acc[nt][r];
        }
    } else if (bx < 144) {
        int z = bx - 128;
        float* s1 = (float*)sm;
        float* s2 = s1 + 256;
        float mx1 = 0.f, mx2 = 0.f;
        for (int jj = t; jj < 512; jj += 256) {
            float rs = 0.f, cs = 0.f;
#pragma unroll
            for (int ti = 0; ti < 4; ++ti) {
                rs += rsum[(z * 4 + ti) * 512 + jj];
                cs += csum[(z * 4 + ti) * 512 + jj];
            }
            mx1 = fmaxf(mx1, rs);
            mx2 = fmaxf(mx2, cs);
        }
        s1[t] = mx1; s2[t] = mx2;
        __syncthreads();
        for (int off = 128; off > 0; off >>= 1) {
            if (t < off) {
                s1[t] = fmaxf(s1[t], s1[t + off]);
                s2[t] = fmaxf(s2[t], s2[t + off]);
            }
            __syncthreads();
        }
        if (t == 0) scal[z] = 1.0f / (s1[0] * s2[0]);
    } else {
        int h = bx - 144;
        for (int jj = t; jj < 512; jj += 256) {
            float s = 0.f, q = 0.f;
#pragma unroll
            for (int b = 0; b < 2; ++b)
#pragma unroll
                for (int ti = 0; ti < 4; ++ti) {
                    int zz = b * 8 + h;
                    s += rsum[(zz * 4 + ti) * 512 + jj];
                    q += rsq [(zz * 4 + ti) * 512 + jj];
                }
            float m_ = s / 1024.f;
            float var = (q - s * s / 1024.f) / 1023.f;
            inv_sig[h * 512 + jj] = 1.0f / sqrtf(var + 1e-5f);
            mu[h * 512 + jj] = m_;
        }
    }
}

// ============ fg_k<MODE>: symmetric fp16 GEMM, 64x64 lower tiles + mirror (36x16 blocks) ============
// MODE 0: T0 = -s * A@A^T (kend=col0+64).  MODE 1: T' = 2*V + A@A^T (full K).
template<int MODE>
__global__ __launch_bounds__(256) void fg_k(const _Float16* __restrict__ A,
                                            const _Float16* V,
                                            _Float16* __restrict__ R,
                                            const float* __restrict__ scal)
{
    const int tIs[36] = {0,1,1,2,2,2,3,3,3,3,4,4,4,4,4,5,5,5,5,5,5,6,6,6,6,6,6,6,7,7,7,7,7,7,7,7};
    const int tJs[36] = {0,0,1,0,1,2,0,1,2,3,0,1,2,3,4,0,1,2,3,4,5,0,1,2,3,4,5,6,0,1,2,3,4,5,6,7};
    __shared__ _Float16 As[64][40];
    __shared__ _Float16 Bs[64][40];
    const int z = blockIdx.y;
    const long zo = (long)z * Ss * Ss;
    const int ti = tIs[blockIdx.x], tj = tJs[blockIdx.x];
    const int row0 = ti * 64, col0 = tj * 64;
    const bool diag = (ti == tj);
    const int kend = (MODE == 0) ? (col0 + 64) : Ss;
    const int t = threadIdx.x;
    const int wave = t >> 6, lane = t & 63;
    const int ln = lane & 15, quad = lane >> 4;
    const int r4 = t >> 2, c4 = (t & 3) * 8;

    f32x4 acc[4];
#pragma unroll
    for (int i = 0; i < 4; ++i) acc[i] = (f32x4){0.f, 0.f, 0.f, 0.f};

    const long aoff = zo + (long)(row0 + r4) * Ss;
    const long boff = zo + (long)(col0 + r4) * Ss;
    uint4 ua = *(const uint4*)&A[aoff + c4];
    uint4 ub = *(const uint4*)&A[boff + c4];

    for (int k0 = 0; k0 < kend; k0 += 32) {
        *(uint4*)&As[r4][c4] = ua;
        *(uint4*)&Bs[r4][c4] = ub;
        __syncthreads();
        int kn = k0 + 32;
        if (kn < kend) {
            ua = *(const uint4*)&A[aoff + kn + c4];
            ub = *(const uint4*)&A[boff + kn + c4];
        }
        f16x8 af = *(const f16x8*)&As[wave * 16 + ln][quad * 8];
#pragma unroll
        for (int nt = 0; nt < 4; ++nt) {
            f16x8 bf = *(const f16x8*)&Bs[nt * 16 + ln][quad * 8];
            acc[nt] = __builtin_amdgcn_mfma_f32_16x16x32_f16(af, bf, acc[nt], 0, 0, 0);
        }
        __syncthreads();
    }

    float s = (MODE == 0) ? scal[z] : 0.f;
    const int gr0 = row0 + wave * 16 + quad * 4;
#pragma unroll
    for (int nt = 0; nt < 4; ++nt) {
        const int gc = col0 + nt * 16 + ln;
        _Float16 rb[4] __attribute__((aligned(8)));
#pragma unroll
        for (int r = 0; r < 4; ++r) {
            const long gi = zo + (long)(gr0 + r) * Ss + gc;
            float val;
            if (MODE == 0) val = -s * acc[nt][r];
            else           val = 2.0f * (float)V[gi] + acc[nt][r];
            _Float16 o = (_Float16)val;
            R[gi] = o;
            rb[r] = o;
        }
        if (!diag)
            *(uint2*)&R[zo + (long)gc * Ss + gr0] = *(const uint2*)rb;
    }
}

// ============ yk_k: y' = 2*y + y x T, split-K=2, fp32 half-buffers ============
// grid (16, 16): bx = kh*8 + cc. Reads (A0,A1) fp32 halves, T fp16; writes Okh fp32.
__global__ __launch_bounds__(256) void yk_k(const float* __restrict__ A0,
                                            const float* __restrict__ A1,
                                            const _Float16* __restrict__ T,
                                            float* __restrict__ O0,
                                            float* __restrict__ O1)
{
    __shared__ __align__(16) char sm[10240];
    const int z = blockIdx.y;
    const int cc = blockIdx.x & 7, kh = blockIdx.x >> 3;
    const int col0 = cc * 64;
    const long zA = (long)z * (HD * Ss);
    const long zB = (long)z * Ss * Ss;
    const int t = threadIdx.x;
    const int wave = t >> 6, lane = t & 63;
    const int ln = lane & 15, quad = lane >> 4;

    f32x4 acc[4];
#pragma unroll
    for (int i = 0; i < 4; ++i) acc[i] = (f32x4){0.f, 0.f, 0.f, 0.f};
    wk_core32(sm, A0, A1, T, zA, zB, col0, kh * 256, kh * 256 + 256, acc);

    float* O = kh ? O1 : O0;
    const int gr = wave * 16 + quad * 4;
#pragma unroll
    for (int nt = 0; nt < 4; ++nt) {
        const int gc = col0 + nt * 16 + ln;
#pragma unroll
        for (int r = 0; r < 4; ++r) {
            const long idx = zA + (long)(gr + r) * Ss + gc;
            float val = acc[nt][r];
            if (kh == 0) val += 2.0f * (A0[idx] + A1[idx]);
            O[idx] = val;
        }
    }
}

// ============ c2s_k: c2sT = inv_sig[n]*s*(y x Wt) + negoff partials ============
__global__ __launch_bounds__(256) void c2s_k(const float* __restrict__ A0,
                                             const float* __restrict__ A1,
                                             const _Float16* __restrict__ Wt,
                                             _Float16* __restrict__ c2sT,
                                             const float* __restrict__ scal,
                                             const float* __restrict__ inv_sig,
                                             const float* __restrict__ mu,
                                             float* __restrict__ negopart)
{
    __shared__ __align__(16) char sm[10240];
    __shared__ float red[64];
    const int z = blockIdx.y;
    const int h = z & 7;
    const int col0 = blockIdx.x * 64;
    const long zA = (long)z * (HD * Ss);
    const long zB = (long)z * Ss * Ss;
    const int t = threadIdx.x;
    const int wave = t >> 6, lane = t & 63;
    const int ln = lane & 15, quad = lane >> 4;

    f32x4 acc[4];
#pragma unroll
    for (int i = 0; i < 4; ++i) acc[i] = (f32x4){0.f, 0.f, 0.f, 0.f};
    wk_core32(sm, A0, A1, Wt, zA, zB, col0, col0, Ss, acc);

    if (t < 64) red[t] = 0.f;
    __syncthreads();
    const int gr = wave * 16 + quad * 4;
    float pr[4] = {0.f, 0.f, 0.f, 0.f};
    float s = scal[z];
#pragma unroll
    for (int nt = 0; nt < 4; ++nt) {
        const int gc = col0 + nt * 16 + ln;
#pragma unroll
        for (int r = 0; r < 4; ++r) {
            float val = inv_sig[h * 512 + gc] * (s * acc[nt][r]);
            pr[r] += mu[h * 512 + gc] * val;
            c2sT[zA + (long)(gr + r) * Ss + gc] = (_Float16)val;
        }
    }
#pragma unroll
    for (int r = 0; r < 4; ++r)
        atomicAdd(&red[gr + r], pr[r]);
    __syncthreads();
    if (t < 64)
        negopart[(z * 8 + blockIdx.x) * 64 + t] = red[t];
}

// ============ ga_k: gat = Wh @ c2s - neg, fp32 out in [B,S,DIM] ============
__global__ __launch_bounds__(256) void ga_k(const _Float16* __restrict__ Wh,
                                            const _Float16* __restrict__ c2sT,
                                            const float* __restrict__ negopart,
                                            float* __restrict__ gat)
{
    __shared__ __align__(16) char sm[10240];
    __shared__ float neg[64];
    const int z = blockIdx.y;
    const int b = z >> 3, h = z & 7;
    const int m0 = blockIdx.x * 64;
    const long zA = (long)z * Ss * Ss;
    const long zB = (long)z * (HD * Ss);
    const int t = threadIdx.x;
    const int wave = t >> 6, lane = t & 63;
    const int ln = lane & 15, quad = lane >> 4;

    if (t < 64) {
        float s = 0.f;
#pragma unroll
        for (int k = 0; k < 8; ++k) s += negopart[(z * 8 + k) * 64 + t];
        neg[t] = s;
    }
    __syncthreads();

    f32x4 acc[4];
#pragma unroll
    for (int i = 0; i < 4; ++i) acc[i] = (f32x4){0.f, 0.f, 0.f, 0.f};
    wk_core(sm, c2sT, Wh, zB, zA, m0, 0, m0 + 64, acc);

    const int gr = wave * 16 + quad * 4;   // d index
#pragma unroll
    for (int nt = 0; nt < 4; ++nt) {
        const int m = m0 + nt * 16 + ln;
#pragma unroll
        for (int r = 0; r < 4; ++r) {
            const int d = gr + r;
            gat[(long)b * (Ss * DIM) + (long)m * DIM + h * HD + d] = acc[nt][r] - neg[d];
        }
    }
}

extern "C" void kernel_launch(void* const* d_in, const int* in_sizes, int n_in,
                              void* d_out, int out_size, void* d_ws, size_t ws_size,
                              hipStream_t stream)
{
    const float* x      = (const float*)d_in[0];
    const float* qkv_w  = (const float*)d_in[1];
    const float* qkv_b  = (const float*)d_in[2];
    const float* proj_w = (const float*)d_in[3];
    const float* proj_b = (const float*)d_in[4];
    float* out = (float*)d_out;
    float* ws  = (float*)d_ws;

    float* qkv     = ws;
    _Float16* Wh   = (_Float16*)(ws + 1572864);
    _Float16* Wt   = (_Float16*)(ws + 3670016);
    _Float16* vT   = (_Float16*)(ws + 5767168);
    _Float16* T[5];
    for (int i = 0; i < 5; ++i) T[i] = (_Float16*)(ws + 6029312 + (long)i * 2097152);
    float* Ya0 = ws + 16515072;   // fp32 y half-buffers, 524288 f each
    float* Ya1 = ws + 17039360;
    float* Yb0 = ws + 17563648;
    float* Yb1 = ws + 18087936;
    float* Zb  = ws + 18612224;
    _Float16* c2sT = (_Float16*)(ws + 19136512);
    float* rsum    = ws + 19398656;
    float* rsq     = ws + 19431424;
    float* csum    = ws + 19464192;
    float* scal    = ws + 19496960;
    float* mu      = ws + 19496976;
    float* inv_sig = ws + 19501072;
    float* negp    = ws + 19505168;
    float* gat     = ws + 19513360;

    dim3 blk(256);

    // 0. zero buffer for y0's missing K-half
    hipMemsetAsync(Zb, 0, 524288 * sizeof(float), stream);

    // 1. qkv = x @ qkv_w^T + qkv_b
    mm_k<<<dim3(12, 8), blk, 0, stream>>>(x, qkv_w, qkv_b, qkv, DIM, 3 * DIM);

    // 2. W fp16 (both layouts) + reduction partials + vT
    wt_fused<<<dim3(18, 16), blk, 0, stream>>>(qkv, Wh, Wt, vT, rsum, rsq, csum);

    // 3. y0 = vT x Wt (fp32)  ||  scale + whitening stats
    mid_k<<<dim3(152), blk, 0, stream>>>(vT, Wt, Ya0, rsum, rsq, csum, scal, mu, inv_sig);

    // 4. T0 = -s * W W^T  (symmetric, 36 lower 64-tiles + mirror)
    fg_k<0><<<dim3(36, 16), blk, 0, stream>>>(Wh, nullptr, T[0], scal);

    // 5-8. residual squarings: T' = 2T + T^2
    for (int i = 0; i < 4; ++i)
        fg_k<1><<<dim3(36, 16), blk, 0, stream>>>(T[i], T[i], T[i + 1], nullptr);

    // 9-13. y <- 2y + y T_k, k = 4..0  (split-K=2, fp32 half-buffers)
    float *ca0 = Ya0, *ca1 = Zb, *na0 = Yb0, *na1 = Yb1;
    for (int k = 4; k >= 0; --k) {
        yk_k<<<dim3(16, 16), blk, 0, stream>>>(ca0, ca1, T[k], na0, na1);
        if (ca0 == Ya0 && ca1 == Zb) { ca0 = na0; ca1 = na1; na0 = Ya0; na1 = Ya1; }
        else { float* t0 = ca0; float* t1 = ca1; ca0 = na0; ca1 = na1; na0 = t0; na1 = t1; }
    }

    // 14. c2sT = inv_sig * s * (y W) + negoff partials
    c2s_k<<<dim3(8, 16), blk, 0, stream>>>(ca0, ca1, Wt, c2sT, scal, inv_sig, mu, negp);

    // 15. gat = W @ c2s - neg
    ga_k<<<dim3(8, 16), blk, 0, stream>>>(Wh, c2sT, negp, gat);

    // 16. out = gat @ proj_w^T + proj_b
    mm_k<<<dim3(4, 8), blk, 0, stream>>>(gat, proj_w, proj_b, out, DIM, DIM);
}

// Round 11
// 311.679 us; speedup vs baseline: 1.1352x; 1.1352x over previous
//
#include <hip/hip_runtime.h>

#define Bq 2
#define Hh 8
#define Ss 512
#define HD 64
#define DIM 512

using f32x4   = __attribute__((ext_vector_type(4))) float;
using bf16x8s = __attribute__((ext_vector_type(8))) short;
typedef _Float16 f16x8 __attribute__((ext_vector_type(8)));

__device__ __forceinline__ float bf2f(unsigned short u) {
    return __uint_as_float(((unsigned int)u) << 16);
}
__device__ __forceinline__ unsigned short f2bf(float f) {
    unsigned int u = __float_as_uint(f);
    u = (u + 0x7FFFu + ((u >> 16) & 1u)) >> 16;   // RNE
    return (unsigned short)u;
}

// ============ mm_k: C = A @ B^T + bias (fp32 io, split bf16x2 MFMA, 128x128) ============
__global__ __launch_bounds__(256) void mm_k(
    const float* __restrict__ A, const float* __restrict__ B,
    const float* __restrict__ bias, float* __restrict__ C,
    int K, int ldc)
{
    const int row0 = blockIdx.y * 128, col0 = blockIdx.x * 128;
    __shared__ unsigned short AsH[128][40], AsL[128][40];
    __shared__ unsigned short BsH[128][40], BsL[128][40];
    const int t = threadIdx.x;
    const int wave = t >> 6, lane = t & 63;
    const int ln = lane & 15, quad = lane >> 4;
    const int wm = (wave & 1) * 64, wn = (wave >> 1) * 64;

    f32x4 acc[4][4];
#pragma unroll
    for (int i = 0; i < 4; ++i)
#pragma unroll
        for (int j = 0; j < 4; ++j)
            acc[i][j] = (f32x4){0.f, 0.f, 0.f, 0.f};

    const int sr = t >> 2, sg = (t & 3) * 8;

    for (int k0 = 0; k0 < K; k0 += 32) {
        __syncthreads();
#pragma unroll
        for (int half = 0; half < 4; ++half) {
            const float* src = (half < 2) ? A : B;
            int base = (half < 2) ? row0 : col0;
            int row = sr + ((half & 1) ? 64 : 0);
            const float* p = &src[(long)(base + row) * K + k0 + sg];
            float4 f0 = *(const float4*)p;
            float4 f1 = *(const float4*)(p + 4);
            float fv[8] = {f0.x, f0.y, f0.z, f0.w, f1.x, f1.y, f1.z, f1.w};
            unsigned short hv[8], lv[8];
#pragma unroll
            for (int e = 0; e < 8; ++e) {
                hv[e] = f2bf(fv[e]);
                lv[e] = f2bf(fv[e] - bf2f(hv[e]));
            }
            uint4 H, L;
            H.x = hv[0] | (hv[1] << 16); H.y = hv[2] | (hv[3] << 16);
            H.z = hv[4] | (hv[5] << 16); H.w = hv[6] | (hv[7] << 16);
            L.x = lv[0] | (lv[1] << 16); L.y = lv[2] | (lv[3] << 16);
            L.z = lv[4] | (lv[5] << 16); L.w = lv[6] | (lv[7] << 16);
            if (half < 2) { *(uint4*)&AsH[row][sg] = H; *(uint4*)&AsL[row][sg] = L; }
            else          { *(uint4*)&BsH[row][sg] = H; *(uint4*)&BsL[row][sg] = L; }
        }
        __syncthreads();

        bf16x8s afH[4], afL[4], bfH[4], bfL[4];
#pragma unroll
        for (int mt = 0; mt < 4; ++mt) {
            afH[mt] = *(const bf16x8s*)&AsH[wm + mt * 16 + ln][quad * 8];
            afL[mt] = *(const bf16x8s*)&AsL[wm + mt * 16 + ln][quad * 8];
        }
#pragma unroll
        for (int nt = 0; nt < 4; ++nt) {
            bfH[nt] = *(const bf16x8s*)&BsH[wn + nt * 16 + ln][quad * 8];
            bfL[nt] = *(const bf16x8s*)&BsL[wn + nt * 16 + ln][quad * 8];
        }
#pragma unroll
        for (int mt = 0; mt < 4; ++mt)
#pragma unroll
            for (int nt = 0; nt < 4; ++nt) {
                acc[mt][nt] = __builtin_amdgcn_mfma_f32_16x16x32_bf16(afH[mt], bfH[nt], acc[mt][nt], 0, 0, 0);
                acc[mt][nt] = __builtin_amdgcn_mfma_f32_16x16x32_bf16(afH[mt], bfL[nt], acc[mt][nt], 0, 0, 0);
                acc[mt][nt] = __builtin_amdgcn_mfma_f32_16x16x32_bf16(afL[mt], bfH[nt], acc[mt][nt], 0, 0, 0);
            }
    }

#pragma unroll
    for (int mt = 0; mt < 4; ++mt) {
        const int gr0 = row0 + wm + mt * 16 + quad * 4;
#pragma unroll
        for (int nt = 0; nt < 4; ++nt) {
            const int gc = col0 + wn + nt * 16 + ln;
            float bb = bias[gc];
#pragma unroll
            for (int r = 0; r < 4; ++r)
                C[(long)(gr0 + r) * ldc + gc] = acc[mt][nt][r] + bb;
        }
    }
}

// ============ wt_fused: 64x64 tiles, W fp16 (both layouts) + partials + vT ============
// grid (66, 16): bx<64 -> tile (ti=bx>>3, tj=bx&7); bx 64/65 -> vT pack half.
// partials at 64-granularity: rsum/rsq slot [(z*8+ti)*512 + j], csum [(z*8+tj)*512 + i].
__global__ __launch_bounds__(256) void wt_fused(const float* __restrict__ qkv,
                                                _Float16* __restrict__ Wh,
                                                _Float16* __restrict__ Wt,
                                                _Float16* __restrict__ vT,
                                                float* __restrict__ rsum,
                                                float* __restrict__ rsq,
                                                float* __restrict__ csum)
{
    __shared__ float qs[32][64];
    __shared__ float ks[32][64];
    __shared__ float colacc[64];
    int z = blockIdx.y;
    int b = z >> 3, h = z & 7;
    int t = threadIdx.x;
    int bx = blockIdx.x;
    long zo = (long)z * Ss * Ss;

    if (bx >= 64) {            // vT pack: half dh (d 32-chunk), all k
        float (*sT)[33] = (float(*)[33])qs;
        int dt = (bx - 64) * 32;
        int d = t & 31, kr = t >> 5;
        for (int kt = 0; kt < Ss; kt += 32) {
            __syncthreads();
#pragma unroll
            for (int p = 0; p < 4; ++p) {
                int kk = kr + p * 8;
                sT[kk][d] = qkv[(long)b * (Ss * 3 * DIM) + (long)(kt + kk) * (3 * DIM) + 2 * DIM + h * HD + dt + d];
            }
            __syncthreads();
#pragma unroll
            for (int p = 0; p < 4; ++p) {
                int dd = kr + p * 8;
                vT[(long)z * (HD * Ss) + (long)(dt + dd) * Ss + kt + d] = (_Float16)sT[d][dd];
            }
        }
        return;
    }

    int ti = bx >> 3, tj = bx & 7;
    int i0 = ti * 64, j0 = tj * 64;

    if (tj > ti) {             // fully-masked: zero both layouts + partial slots
        uint4 zz = make_uint4(0, 0, 0, 0);
        int row = t >> 2, c16 = (t & 3) * 16;
        *(uint4*)&Wt[zo + (long)(j0 + row) * Ss + i0 + c16]     = zz;
        *(uint4*)&Wt[zo + (long)(j0 + row) * Ss + i0 + c16 + 8] = zz;
        *(uint4*)&Wh[zo + (long)(i0 + row) * Ss + j0 + c16]     = zz;
        *(uint4*)&Wh[zo + (long)(i0 + row) * Ss + j0 + c16 + 8] = zz;
        if (t < 64) {
            rsum[((z * 8 + ti) * 512) + j0 + t] = 0.f;
            rsq [((z * 8 + ti) * 512) + j0 + t] = 0.f;
            csum[((z * 8 + tj) * 512) + i0 + t] = 0.f;
        }
        return;
    }

    int ia = (t & 15) * 4;
    int ja = (t >> 4) * 4;
    const float* qb = qkv + (long)b * Ss * (3 * DIM) + h * HD;
    const float* kb = qb + DIM;
    float acc[4][4] = {};

    for (int d0 = 0; d0 < 64; d0 += 32) {
        __syncthreads();
        int row = t & 63, dg = (t >> 6) * 8;
        float4 qv  = *(const float4*)&qb[(long)(i0 + row) * (3 * DIM) + d0 + dg];
        float4 qv2 = *(const float4*)&qb[(long)(i0 + row) * (3 * DIM) + d0 + dg + 4];
        float4 kv  = *(const float4*)&kb[(long)(j0 + row) * (3 * DIM) + d0 + dg];
        float4 kv2 = *(const float4*)&kb[(long)(j0 + row) * (3 * DIM) + d0 + dg + 4];
        qs[dg+0][row] = qv.x;  qs[dg+1][row] = qv.y;  qs[dg+2][row] = qv.z;  qs[dg+3][row] = qv.w;
        qs[dg+4][row] = qv2.x; qs[dg+5][row] = qv2.y; qs[dg+6][row] = qv2.z; qs[dg+7][row] = qv2.w;
        ks[dg+0][row] = kv.x;  ks[dg+1][row] = kv.y;  ks[dg+2][row] = kv.z;  ks[dg+3][row] = kv.w;
        ks[dg+4][row] = kv2.x; ks[dg+5][row] = kv2.y; ks[dg+6][row] = kv2.z; ks[dg+7][row] = kv2.w;
        __syncthreads();
#pragma unroll
        for (int d = 0; d < 32; ++d) {
            float4 q0 = *(const float4*)&qs[d][ia];
            float4 k0 = *(const float4*)&ks[d][ja];
            float qv_[4] = {q0.x, q0.y, q0.z, q0.w};
            float kv_[4] = {k0.x, k0.y, k0.z, k0.w};
#pragma unroll
            for (int aa = 0; aa < 4; ++aa)
#pragma unroll
                for (int c = 0; c < 4; ++c)
                    acc[aa][c] += fabsf(qv_[aa] - kv_[c]);
        }
    }

#pragma unroll
    for (int aa = 0; aa < 4; ++aa) {
        int i = i0 + ia + aa;
#pragma unroll
        for (int c = 0; c < 4; ++c) {
            int j = j0 + ja + c;
            float e = expf(-acc[aa][c] * 0.25f);
            acc[aa][c] = (j <= i) ? e : 0.0f;
        }
    }
    // Wt rows + per-j partials
#pragma unroll
    for (int c = 0; c < 4; ++c) {
        int j = j0 + ja + c;
        float rs = 0.f, rq = 0.f;
#pragma unroll
        for (int aa = 0; aa < 4; ++aa) { rs += acc[aa][c]; rq += acc[aa][c] * acc[aa][c]; }
        _Float16 ha[4] __attribute__((aligned(8))) = {(_Float16)acc[0][c], (_Float16)acc[1][c], (_Float16)acc[2][c], (_Float16)acc[3][c]};
        *(uint2*)&Wt[zo + (long)j * Ss + i0 + ia] = *(const uint2*)ha;
#pragma unroll
        for (int off = 8; off > 0; off >>= 1) {
            rs += __shfl_down(rs, off, 16);
            rq += __shfl_down(rq, off, 16);
        }
        if ((t & 15) == 0) {
            rsum[((z * 8 + ti) * 512) + j] = rs;
            rsq [((z * 8 + ti) * 512) + j] = rq;
        }
    }
    // Wh rows
#pragma unroll
    for (int aa = 0; aa < 4; ++aa) {
        int i = i0 + ia + aa;
        _Float16 hb[4] __attribute__((aligned(8))) = {(_Float16)acc[aa][0], (_Float16)acc[aa][1], (_Float16)acc[aa][2], (_Float16)acc[aa][3]};
        *(uint2*)&Wh[zo + (long)i * Ss + j0 + ja] = *(const uint2*)hb;
    }
    // per-i partials via LDS
    __syncthreads();
    if (t < 64) colacc[t] = 0.f;
    __syncthreads();
#pragma unroll
    for (int aa = 0; aa < 4; ++aa) {
        float cs = acc[aa][0] + acc[aa][1] + acc[aa][2] + acc[aa][3];
        atomicAdd(&colacc[ia + aa], cs);
    }
    __syncthreads();
    if (t < 64) csum[((z * 8 + tj) * 512) + i0 + t] = colacc[t];
}

// ============ fp16-A wide core (pipelined): acc += A[64xK] x B[64-chunk x K] ============
__device__ __forceinline__ void wk_core(char* smc, const _Float16* A, const _Float16* B,
                                        long zA, long zB, int col0, int kbeg, int kend,
                                        f32x4* acc)
{
    _Float16 (*As)[40] = (_Float16(*)[40])smc;
    _Float16 (*Bs)[40] = (_Float16(*)[40])(smc + 5120);
    const int t = threadIdx.x;
    const int wave = t >> 6, lane = t & 63;
    const int ln = lane & 15, quad = lane >> 4;
    const int r4 = t >> 2, c4 = (t & 3) * 8;
    const long aoff = zA + (long)r4 * Ss;
    const long boff = zB + (long)(col0 + r4) * Ss;

    uint4 ua = *(const uint4*)&A[aoff + kbeg + c4];
    uint4 ub = *(const uint4*)&B[boff + kbeg + c4];
    for (int k0 = kbeg; k0 < kend; k0 += 32) {
        *(uint4*)&As[r4][c4] = ua;
        *(uint4*)&Bs[r4][c4] = ub;
        __syncthreads();
        int kn = k0 + 32;
        if (kn < kend) {
            ua = *(const uint4*)&A[aoff + kn + c4];
            ub = *(const uint4*)&B[boff + kn + c4];
        }
        f16x8 af = *(const f16x8*)&As[wave * 16 + ln][quad * 8];
#pragma unroll
        for (int nt = 0; nt < 4; ++nt) {
            f16x8 bf = *(const f16x8*)&Bs[nt * 16 + ln][quad * 8];
            acc[nt] = __builtin_amdgcn_mfma_f32_16x16x32_f16(af, bf, acc[nt], 0, 0, 0);
        }
        __syncthreads();
    }
}

// ============ fp32-halves-A wide core: A = A0+A1 (fp32), converted in staging ============
__device__ __forceinline__ void wk_core32(char* smc, const float* A0, const float* A1,
                                          const _Float16* B, long zA, long zB, int col0,
                                          int kbeg, int kend, f32x4* acc)
{
    _Float16 (*As)[40] = (_Float16(*)[40])smc;
    _Float16 (*Bs)[40] = (_Float16(*)[40])(smc + 5120);
    const int t = threadIdx.x;
    const int wave = t >> 6, lane = t & 63;
    const int ln = lane & 15, quad = lane >> 4;
    const int r4 = t >> 2, c4 = (t & 3) * 8;
    const long aoff = zA + (long)r4 * Ss;
    const long boff = zB + (long)(col0 + r4) * Ss;

    float4 p0 = *(const float4*)&A0[aoff + kbeg + c4];
    float4 p1 = *(const float4*)&A0[aoff + kbeg + c4 + 4];
    float4 q0 = *(const float4*)&A1[aoff + kbeg + c4];
    float4 q1 = *(const float4*)&A1[aoff + kbeg + c4 + 4];
    uint4 ub = *(const uint4*)&B[boff + kbeg + c4];
    for (int k0 = kbeg; k0 < kend; k0 += 32) {
        _Float16 hv[8] __attribute__((aligned(16)));
        hv[0] = (_Float16)(p0.x + q0.x); hv[1] = (_Float16)(p0.y + q0.y);
        hv[2] = (_Float16)(p0.z + q0.z); hv[3] = (_Float16)(p0.w + q0.w);
        hv[4] = (_Float16)(p1.x + q1.x); hv[5] = (_Float16)(p1.y + q1.y);
        hv[6] = (_Float16)(p1.z + q1.z); hv[7] = (_Float16)(p1.w + q1.w);
        *(uint4*)&As[r4][c4] = *(const uint4*)hv;
        *(uint4*)&Bs[r4][c4] = ub;
        __syncthreads();
        int kn = k0 + 32;
        if (kn < kend) {
            p0 = *(const float4*)&A0[aoff + kn + c4];
            p1 = *(const float4*)&A0[aoff + kn + c4 + 4];
            q0 = *(const float4*)&A1[aoff + kn + c4];
            q1 = *(const float4*)&A1[aoff + kn + c4 + 4];
            ub = *(const uint4*)&B[boff + kn + c4];
        }
        f16x8 af = *(const f16x8*)&As[wave * 16 + ln][quad * 8];
#pragma unroll
        for (int nt = 0; nt < 4; ++nt) {
            f16x8 bf = *(const f16x8*)&Bs[nt * 16 + ln][quad * 8];
            acc[nt] = __builtin_amdgcn_mfma_f32_16x16x32_f16(af, bf, acc[nt], 0, 0, 0);
        }
        __syncthreads();
    }
}

// ============ mid_k: blocks 0..127 -> y0 = vT x Wt (fp32); 128..151 -> fin (8 partials) ============
__global__ __launch_bounds__(256) void mid_k(const _Float16* __restrict__ vT,
                                             const _Float16* __restrict__ Wt,
                                             float* __restrict__ y0,
                                             const float* __restrict__ rsum,
                                             const float* __restrict__ rsq,
                                             const float* __restrict__ csum,
                                             float* __restrict__ scal,
                                             float* __restrict__ mu,
                                             float* __restrict__ inv_sig)
{
    __shared__ __align__(16) char sm[10240];
    int bx = blockIdx.x, t = threadIdx.x;
    if (bx < 128) {
        int z = bx >> 3, cc = bx & 7;
        int col0 = cc * 64;
        long zA = (long)z * (HD * Ss), zB = (long)z * Ss * Ss;
        f32x4 acc[4];
#pragma unroll
        for (int i = 0; i < 4; ++i) acc[i] = (f32x4){0.f, 0.f, 0.f, 0.f};
        wk_core(sm, vT, Wt, zA, zB, col0, col0, Ss, acc);
        const int wave = t >> 6, lane = t & 63;
        const int ln = lane & 15, quad = lane >> 4;
        const int gr = wave * 16 + quad * 4;
#pragma unroll
        for (int nt = 0; nt < 4; ++nt) {
            const int gc = col0 + nt * 16 + ln;
#pragma unroll
            for (int r = 0; r < 4; ++r)
                y0[zA + (long)(gr + r) * Ss + gc] = acc[nt][r];
        }
    } else if (bx < 144) {
        int z = bx - 128;
        float* s1 = (float*)sm;
        float* s2 = s1 + 256;
        float mx1 = 0.f, mx2 = 0.f;
        for (int jj = t; jj < 512; jj += 256) {
            float rs = 0.f, cs = 0.f;
#pragma unroll
            for (int ti = 0; ti < 8; ++ti) {
                rs += rsum[(z * 8 + ti) * 512 + jj];
                cs += csum[(z * 8 + ti) * 512 + jj];
            }
            mx1 = fmaxf(mx1, rs);
            mx2 = fmaxf(mx2, cs);
        }
        s1[t] = mx1; s2[t] = mx2;
        __syncthreads();
        for (int off = 128; off > 0; off >>= 1) {
            if (t < off) {
                s1[t] = fmaxf(s1[t], s1[t + off]);
                s2[t] = fmaxf(s2[t], s2[t + off]);
            }
            __syncthreads();
        }
        if (t == 0) scal[z] = 1.0f / (s1[0] * s2[0]);
    } else {
        int h = bx - 144;
        for (int jj = t; jj < 512; jj += 256) {
            float s = 0.f, q = 0.f;
#pragma unroll
            for (int b = 0; b < 2; ++b)
#pragma unroll
                for (int ti = 0; ti < 8; ++ti) {
                    int zz = b * 8 + h;
                    s += rsum[(zz * 8 + ti) * 512 + jj];
                    q += rsq [(zz * 8 + ti) * 512 + jj];
                }
            float m_ = s / 1024.f;
            float var = (q - s * s / 1024.f) / 1023.f;
            inv_sig[h * 512 + jj] = 1.0f / sqrtf(var + 1e-5f);
            mu[h * 512 + jj] = m_;
        }
    }
}

// ============ fg_k<MODE>: symmetric fp16 GEMM, 64x64 lower tiles + mirror (36x16 blocks) ============
// MODE 0: T0 = -s * A@A^T (kend=col0+64).  MODE 1: T' = 2*V + A@A^T (full K).
template<int MODE>
__global__ __launch_bounds__(256) void fg_k(const _Float16* __restrict__ A,
                                            const _Float16* V,
                                            _Float16* __restrict__ R,
                                            const float* __restrict__ scal)
{
    const int tIs[36] = {0,1,1,2,2,2,3,3,3,3,4,4,4,4,4,5,5,5,5,5,5,6,6,6,6,6,6,6,7,7,7,7,7,7,7,7};
    const int tJs[36] = {0,0,1,0,1,2,0,1,2,3,0,1,2,3,4,0,1,2,3,4,5,0,1,2,3,4,5,6,0,1,2,3,4,5,6,7};
    __shared__ _Float16 As[64][40];
    __shared__ _Float16 Bs[64][40];
    const int z = blockIdx.y;
    const long zo = (long)z * Ss * Ss;
    const int ti = tIs[blockIdx.x], tj = tJs[blockIdx.x];
    const int row0 = ti * 64, col0 = tj * 64;
    const bool diag = (ti == tj);
    const int kend = (MODE == 0) ? (col0 + 64) : Ss;
    const int t = threadIdx.x;
    const int wave = t >> 6, lane = t & 63;
    const int ln = lane & 15, quad = lane >> 4;
    const int r4 = t >> 2, c4 = (t & 3) * 8;

    f32x4 acc[4];
#pragma unroll
    for (int i = 0; i < 4; ++i) acc[i] = (f32x4){0.f, 0.f, 0.f, 0.f};

    const long aoff = zo + (long)(row0 + r4) * Ss;
    const long boff = zo + (long)(col0 + r4) * Ss;
    uint4 ua = *(const uint4*)&A[aoff + c4];
    uint4 ub = *(const uint4*)&A[boff + c4];

    for (int k0 = 0; k0 < kend; k0 += 32) {
        *(uint4*)&As[r4][c4] = ua;
        *(uint4*)&Bs[r4][c4] = ub;
        __syncthreads();
        int kn = k0 + 32;
        if (kn < kend) {
            ua = *(const uint4*)&A[aoff + kn + c4];
            ub = *(const uint4*)&A[boff + kn + c4];
        }
        f16x8 af = *(const f16x8*)&As[wave * 16 + ln][quad * 8];
#pragma unroll
        for (int nt = 0; nt < 4; ++nt) {
            f16x8 bf = *(const f16x8*)&Bs[nt * 16 + ln][quad * 8];
            acc[nt] = __builtin_amdgcn_mfma_f32_16x16x32_f16(af, bf, acc[nt], 0, 0, 0);
        }
        __syncthreads();
    }

    float s = (MODE == 0) ? scal[z] : 0.f;
    const int gr0 = row0 + wave * 16 + quad * 4;
#pragma unroll
    for (int nt = 0; nt < 4; ++nt) {
        const int gc = col0 + nt * 16 + ln;
        _Float16 rb[4] __attribute__((aligned(8)));
#pragma unroll
        for (int r = 0; r < 4; ++r) {
            const long gi = zo + (long)(gr0 + r) * Ss + gc;
            float val;
            if (MODE == 0) val = -s * acc[nt][r];
            else           val = 2.0f * (float)V[gi] + acc[nt][r];
            _Float16 o = (_Float16)val;
            R[gi] = o;
            rb[r] = o;
        }
        if (!diag)
            *(uint2*)&R[zo + (long)gc * Ss + gr0] = *(const uint2*)rb;
    }
}

// ============ yk_k: y' = 2*y + y x T, split-K=2, fp32 half-buffers ============
__global__ __launch_bounds__(256) void yk_k(const float* __restrict__ A0,
                                            const float* __restrict__ A1,
                                            const _Float16* __restrict__ T,
                                            float* __restrict__ O0,
                                            float* __restrict__ O1)
{
    __shared__ __align__(16) char sm[10240];
    const int z = blockIdx.y;
    const int cc = blockIdx.x & 7, kh = blockIdx.x >> 3;
    const int col0 = cc * 64;
    const long zA = (long)z * (HD * Ss);
    const long zB = (long)z * Ss * Ss;
    const int t = threadIdx.x;
    const int wave = t >> 6, lane = t & 63;
    const int ln = lane & 15, quad = lane >> 4;

    f32x4 acc[4];
#pragma unroll
    for (int i = 0; i < 4; ++i) acc[i] = (f32x4){0.f, 0.f, 0.f, 0.f};
    wk_core32(sm, A0, A1, T, zA, zB, col0, kh * 256, kh * 256 + 256, acc);

    float* O = kh ? O1 : O0;
    const int gr = wave * 16 + quad * 4;
#pragma unroll
    for (int nt = 0; nt < 4; ++nt) {
        const int gc = col0 + nt * 16 + ln;
#pragma unroll
        for (int r = 0; r < 4; ++r) {
            const long idx = zA + (long)(gr + r) * Ss + gc;
            float val = acc[nt][r];
            if (kh == 0) val += 2.0f * (A0[idx] + A1[idx]);
            O[idx] = val;
        }
    }
}

// ============ c2s_k: c2sT = inv_sig[n]*s*(y x Wt) + negoff partials ============
__global__ __launch_bounds__(256) void c2s_k(const float* __restrict__ A0,
                                             const float* __restrict__ A1,
                                             const _Float16* __restrict__ Wt,
                                             _Float16* __restrict__ c2sT,
                                             const float* __restrict__ scal,
                                             const float* __restrict__ inv_sig,
                                             const float* __restrict__ mu,
                                             float* __restrict__ negopart)
{
    __shared__ __align__(16) char sm[10240];
    __shared__ float red[64];
    const int z = blockIdx.y;
    const int h = z & 7;
    const int col0 = blockIdx.x * 64;
    const long zA = (long)z * (HD * Ss);
    const long zB = (long)z * Ss * Ss;
    const int t = threadIdx.x;
    const int wave = t >> 6, lane = t & 63;
    const int ln = lane & 15, quad = lane >> 4;

    f32x4 acc[4];
#pragma unroll
    for (int i = 0; i < 4; ++i) acc[i] = (f32x4){0.f, 0.f, 0.f, 0.f};
    wk_core32(sm, A0, A1, Wt, zA, zB, col0, col0, Ss, acc);

    if (t < 64) red[t] = 0.f;
    __syncthreads();
    const int gr = wave * 16 + quad * 4;
    float pr[4] = {0.f, 0.f, 0.f, 0.f};
    float s = scal[z];
#pragma unroll
    for (int nt = 0; nt < 4; ++nt) {
        const int gc = col0 + nt * 16 + ln;
#pragma unroll
        for (int r = 0; r < 4; ++r) {
            float val = inv_sig[h * 512 + gc] * (s * acc[nt][r]);
            pr[r] += mu[h * 512 + gc] * val;
            c2sT[zA + (long)(gr + r) * Ss + gc] = (_Float16)val;
        }
    }
#pragma unroll
    for (int r = 0; r < 4; ++r)
        atomicAdd(&red[gr + r], pr[r]);
    __syncthreads();
    if (t < 64)
        negopart[(z * 8 + blockIdx.x) * 64 + t] = red[t];
}

// ============ ga_k: gat = Wh @ c2s - neg, fp32 out in [B,S,DIM] ============
__global__ __launch_bounds__(256) void ga_k(const _Float16* __restrict__ Wh,
                                            const _Float16* __restrict__ c2sT,
                                            const float* __restrict__ negopart,
                                            float* __restrict__ gat)
{
    __shared__ __align__(16) char sm[10240];
    __shared__ float neg[64];
    const int z = blockIdx.y;
    const int b = z >> 3, h = z & 7;
    const int m0 = blockIdx.x * 64;
    const long zA = (long)z * Ss * Ss;
    const long zB = (long)z * (HD * Ss);
    const int t = threadIdx.x;
    const int wave = t >> 6, lane = t & 63;
    const int ln = lane & 15, quad = lane >> 4;

    if (t < 64) {
        float s = 0.f;
#pragma unroll
        for (int k = 0; k < 8; ++k) s += negopart[(z * 8 + k) * 64 + t];
        neg[t] = s;
    }
    __syncthreads();

    f32x4 acc[4];
#pragma unroll
    for (int i = 0; i < 4; ++i) acc[i] = (f32x4){0.f, 0.f, 0.f, 0.f};
    wk_core(sm, c2sT, Wh, zB, zA, m0, 0, m0 + 64, acc);

    const int gr = wave * 16 + quad * 4;   // d index
#pragma unroll
    for (int nt = 0; nt < 4; ++nt) {
        const int m = m0 + nt * 16 + ln;
#pragma unroll
        for (int r = 0; r < 4; ++r) {
            const int d = gr + r;
            gat[(long)b * (Ss * DIM) + (long)m * DIM + h * HD + d] = acc[nt][r] - neg[d];
        }
    }
}

extern "C" void kernel_launch(void* const* d_in, const int* in_sizes, int n_in,
                              void* d_out, int out_size, void* d_ws, size_t ws_size,
                              hipStream_t stream)
{
    const float* x      = (const float*)d_in[0];
    const float* qkv_w  = (const float*)d_in[1];
    const float* qkv_b  = (const float*)d_in[2];
    const float* proj_w = (const float*)d_in[3];
    const float* proj_b = (const float*)d_in[4];
    float* out = (float*)d_out;
    float* ws  = (float*)d_ws;

    float* qkv     = ws;
    _Float16* Wh   = (_Float16*)(ws + 1572864);
    _Float16* Wt   = (_Float16*)(ws + 3670016);
    _Float16* vT   = (_Float16*)(ws + 5767168);
    _Float16* T[5];
    for (int i = 0; i < 5; ++i) T[i] = (_Float16*)(ws + 6029312 + (long)i * 2097152);
    float* Ya0 = ws + 16515072;   // fp32 y half-buffers, 524288 f each
    float* Ya1 = ws + 17039360;
    float* Yb0 = ws + 17563648;
    float* Yb1 = ws + 18087936;
    float* Zb  = ws + 18612224;
    _Float16* c2sT = (_Float16*)(ws + 19136512);
    float* rsum    = ws + 19398656;   // 65536
    float* rsq     = ws + 19464192;   // 65536
    float* csum    = ws + 19529728;   // 65536
    float* scal    = ws + 19595264;   // 16
    float* mu      = ws + 19595280;   // 4096
    float* inv_sig = ws + 19599376;   // 4096
    float* negp    = ws + 19603472;   // 8192
    float* gat     = ws + 19611664;   // 524288

    dim3 blk(256);

    // 0. zero buffer for y0's missing K-half
    hipMemsetAsync(Zb, 0, 524288 * sizeof(float), stream);

    // 1. qkv = x @ qkv_w^T + qkv_b
    mm_k<<<dim3(12, 8), blk, 0, stream>>>(x, qkv_w, qkv_b, qkv, DIM, 3 * DIM);

    // 2. W fp16 (both layouts, 64-tiles) + reduction partials + vT
    wt_fused<<<dim3(66, 16), blk, 0, stream>>>(qkv, Wh, Wt, vT, rsum, rsq, csum);

    // 3. y0 = vT x Wt (fp32)  ||  scale + whitening stats
    mid_k<<<dim3(152), blk, 0, stream>>>(vT, Wt, Ya0, rsum, rsq, csum, scal, mu, inv_sig);

    // 4. T0 = -s * W W^T  (symmetric, 36 lower 64-tiles + mirror)
    fg_k<0><<<dim3(36, 16), blk, 0, stream>>>(Wh, nullptr, T[0], scal);

    // 5-8. residual squarings: T' = 2T + T^2
    for (int i = 0; i < 4; ++i)
        fg_k<1><<<dim3(36, 16), blk, 0, stream>>>(T[i], T[i], T[i + 1], nullptr);

    // 9-13. y <- 2y + y T_k, k = 4..0  (split-K=2, fp32 half-buffers)
    float *ca0 = Ya0, *ca1 = Zb, *na0 = Yb0, *na1 = Yb1;
    for (int k = 4; k >= 0; --k) {
        yk_k<<<dim3(16, 16), blk, 0, stream>>>(ca0, ca1, T[k], na0, na1);
        if (ca0 == Ya0 && ca1 == Zb) { ca0 = na0; ca1 = na1; na0 = Ya0; na1 = Ya1; }
        else { float* t0 = ca0; float* t1 = ca1; ca0 = na0; ca1 = na1; na0 = t0; na1 = t1; }
    }

    // 14. c2sT = inv_sig * s * (y W) + negoff partials
    c2s_k<<<dim3(8, 16), blk, 0, stream>>>(ca0, ca1, Wt, c2sT, scal, inv_sig, mu, negp);

    // 15. gat = W @ c2s - neg
    ga_k<<<dim3(8, 16), blk, 0, stream>>>(Wh, c2sT, negp, gat);

    // 16. out = gat @ proj_w^T + proj_b
    mm_k<<<dim3(4, 8), blk, 0, stream>>>(gat, proj_w, proj_b, out, DIM, DIM);
}